// Round 2
// baseline (8846.577 us; speedup 1.0000x reference)
//
#include <hip/hip_runtime.h>
#include <math.h>

#define TZ 8
#define TH 96
#define TW 192
#define C 192
#define NHEADS 6
#define HDIM 32
#define LW 144
#define NWIN 1024
#define NTOK 147456
#define NPOS 3312
#define QSCALE 0.17677669529663687f

// chunking: 8 chunks of 128 windows (= 18432 rows) / 18432 token-rows
#define GWIN 128
#define NCHUNK 8
#define RCHUNK (GWIN * LW)          // 18432 rows per chunk
#define QKV_CHUNK ((size_t)RCHUNK * 576)
#define ATTN_CHUNK ((size_t)RCHUNK * 192)
#define HID_CHUNK ((size_t)RCHUNK * 768)   // == QKV_CHUNK + ATTN_CHUNK

// windowed row -> token (with optional roll). Row r in [0, NTOK).
__device__ __forceinline__ int win_row_to_token(int r, int roll) {
    int wi = r / LW, l = r % LW;
    int nz = wi >> 8, nh = (wi >> 4) & 15, nw = wi & 15;
    int iz = l / 72, rr = l % 72, ih = rr / 12, iw = rr % 12;
    int z = nz * 2 + iz, h = nh * 6 + ih, w = nw * 12 + iw;
    if (roll) {
        z = (z + 1) & 7;
        h += 3; if (h >= TH) h -= TH;
        w += 6; if (w >= TW) w -= TW;
    }
    return (z * TH + h) * TW + w;
}

// ---------------- per-token LN stats: mean, rstd ----------------
__global__ __launch_bounds__(256) void stats_kernel(
    const float* __restrict__ x, float* __restrict__ stats)
{
    int wave = threadIdx.x >> 6;
    int lane = threadIdx.x & 63;
    int t = blockIdx.x * 4 + wave;
    const float* xr = x + (size_t)t * C;
    float v0 = xr[lane], v1 = xr[lane + 64], v2 = xr[lane + 128];
    float s = v0 + v1 + v2;
    float sq = v0 * v0 + v1 * v1 + v2 * v2;
    #pragma unroll
    for (int off = 32; off > 0; off >>= 1) {
        s  += __shfl_xor(s, off, 64);
        sq += __shfl_xor(sq, off, 64);
    }
    if (lane == 0) {
        float mean = s * (1.0f / 192.0f);
        float var  = sq * (1.0f / 192.0f) - mean * mean;
        stats[t * 2]     = mean;
        stats[t * 2 + 1] = rsqrtf(var + 1e-5f);
    }
}

// ---------------- fp32 tiled GEMM, 64x64 tile, 4x4 microtile ----------------
// MODE 0: QKV  : A = LN1(x) gathered via window map (+roll); out chunk, q-scale
// MODE 1: PROJ : A = attn chunk; epilogue scatter-add x[token] += acc+bias
// MODE 2: MLP1 : A = LN2(x) (token order); out chunk with exact GELU
// MODE 3: MLP2 : A = hidden chunk; epilogue x[row] += acc+bias
template <int MODE>
__global__ __launch_bounds__(256) void gemm_kernel(
    const float* __restrict__ A,      // x (0/2) or chunk buf (1/3)
    const float* __restrict__ Bw,
    const float* __restrict__ bias,
    float* __restrict__ Cout,         // chunk buf (0/2) or x (1/3)
    const float* __restrict__ stats,  // MODE 0/2
    const float* __restrict__ lng,
    const float* __restrict__ lnb,
    int N, int K, int row0, int roll)
{
    __shared__ float As[16][64];
    __shared__ float Bs[16][64];
    int tid = threadIdx.x;
    int tx = tid & 15, ty = tid >> 4;
    int mb = blockIdx.y * 64, nb = blockIdx.x * 64;
    float acc[4][4] = {};
    int am = tid >> 2, ak = (tid & 3) << 2;
    int bk = tid >> 4, bn = (tid & 15) << 2;

    const float* Arow;
    float mean = 0.0f, rstd = 0.0f;
    if (MODE == 0 || MODE == 2) {
        int gm = row0 + mb + am;
        int src = (MODE == 0) ? win_row_to_token(gm, roll) : gm;
        Arow = A + (size_t)src * C;
        mean = stats[src * 2];
        rstd = stats[src * 2 + 1];
    } else {
        Arow = A + (size_t)(mb + am) * K;   // chunk-local row
    }
    const float* Bptr = Bw + (size_t)bk * N + nb + bn;

    for (int k0 = 0; k0 < K; k0 += 16) {
        float4 av = *(const float4*)(Arow + k0 + ak);
        if (MODE == 0 || MODE == 2) {
            float4 gv = *(const float4*)(lng + k0 + ak);
            float4 bv = *(const float4*)(lnb + k0 + ak);
            av.x = (av.x - mean) * rstd * gv.x + bv.x;
            av.y = (av.y - mean) * rstd * gv.y + bv.y;
            av.z = (av.z - mean) * rstd * gv.z + bv.z;
            av.w = (av.w - mean) * rstd * gv.w + bv.w;
        }
        float4 bv4 = *(const float4*)(Bptr + (size_t)k0 * N);
        As[ak + 0][am] = av.x; As[ak + 1][am] = av.y;
        As[ak + 2][am] = av.z; As[ak + 3][am] = av.w;
        *(float4*)&Bs[bk][bn] = bv4;
        __syncthreads();
        #pragma unroll
        for (int kk = 0; kk < 16; kk++) {
            float4 a4 = *(const float4*)&As[kk][ty << 2];
            float4 b4 = *(const float4*)&Bs[kk][tx << 2];
            float a[4] = {a4.x, a4.y, a4.z, a4.w};
            float bb[4] = {b4.x, b4.y, b4.z, b4.w};
            #pragma unroll
            for (int i = 0; i < 4; i++)
                #pragma unroll
                for (int j = 0; j < 4; j++)
                    acc[i][j] += a[i] * bb[j];
        }
        __syncthreads();
    }

    #pragma unroll
    for (int i = 0; i < 4; i++) {
        int m = mb + (ty << 2) + i;           // chunk-local row
        if (MODE == 1) {
            int t = win_row_to_token(row0 + m, roll);
            float* xrow = Cout + (size_t)t * C;
            #pragma unroll
            for (int j = 0; j < 4; j++) {
                int n = nb + (tx << 2) + j;
                xrow[n] += acc[i][j] + bias[n];
            }
        } else if (MODE == 3) {
            float* xrow = Cout + (size_t)(row0 + m) * C;
            #pragma unroll
            for (int j = 0; j < 4; j++) {
                int n = nb + (tx << 2) + j;
                xrow[n] += acc[i][j] + bias[n];
            }
        } else {
            float* crow = Cout + (size_t)m * N;
            #pragma unroll
            for (int j = 0; j < 4; j++) {
                int n = nb + (tx << 2) + j;
                float v = acc[i][j] + bias[n];
                if (MODE == 0) {
                    if (n < 192) v *= QSCALE;
                    crow[n] = v;
                } else {  // MODE 2
                    crow[n] = 0.5f * v * (1.0f + erff(v * 0.70710678118654752f));
                }
            }
        }
    }
}

// ---------------- Attention: one block per (window-in-chunk, head) ----------------
__global__ __launch_bounds__(192) void attn_kernel(
    const float* __restrict__ qkv, const float* __restrict__ btab,
    const int* __restrict__ pidx_g, const float* __restrict__ amask,
    float* __restrict__ o, int win0, int roll)
{
    __shared__ float ks[LW][HDIM];
    __shared__ float vs[LW][HDIM];
    int wl = blockIdx.x, head = blockIdx.y;
    int wi = win0 + wl;
    int tid = threadIdx.x;
    const float* base = qkv + (size_t)wl * LW * 576;
    for (int idx = tid; idx < LW * HDIM; idx += 192) {
        int j = idx >> 5, dd = idx & 31;
        ks[j][dd] = base[(size_t)j * 576 + 192 + head * 32 + dd];
        vs[j][dd] = base[(size_t)j * 576 + 384 + head * 32 + dd];
    }
    __syncthreads();
    if (tid >= LW) return;
    int i = tid;
    float q[HDIM];
    const float* qrow = base + (size_t)i * 576 + head * 32;
    #pragma unroll
    for (int dd = 0; dd < HDIM; dd++) q[dd] = qrow[dd];
    int wt = wi & 63;
    const int* pr = pidx_g + i * LW;
    const float* mr = amask + ((size_t)wi * LW + i) * LW;
    float mmax = -1e30f, lsum = 0.0f;
    for (int j = 0; j < LW; j++) {
        float s = 0.0f;
        #pragma unroll
        for (int dd = 0; dd < HDIM; dd++) s += q[dd] * ks[j][dd];
        s += btab[((size_t)pr[j] * 64 + wt) * 6 + head];
        if (roll) s += mr[j];
        float nm = fmaxf(mmax, s);
        lsum = lsum * __expf(mmax - nm) + __expf(s - nm);
        mmax = nm;
    }
    float inv = 1.0f / lsum;
    float oacc[HDIM];
    #pragma unroll
    for (int dd = 0; dd < HDIM; dd++) oacc[dd] = 0.0f;
    for (int j = 0; j < LW; j++) {
        float s = 0.0f;
        #pragma unroll
        for (int dd = 0; dd < HDIM; dd++) s += q[dd] * ks[j][dd];
        s += btab[((size_t)pr[j] * 64 + wt) * 6 + head];
        if (roll) s += mr[j];
        float p = __expf(s - mmax) * inv;
        #pragma unroll
        for (int dd = 0; dd < HDIM; dd++) oacc[dd] += p * vs[j][dd];
    }
    float* orow = o + ((size_t)wl * LW + i) * C + head * 32;
    #pragma unroll
    for (int dd = 0; dd < HDIM; dd++) orow[dd] = oacc[dd];
}

extern "C" void kernel_launch(void* const* d_in, const int* in_sizes, int n_in,
                              void* d_out, int out_size, void* d_ws, size_t ws_size,
                              hipStream_t stream)
{
    (void)in_sizes; (void)n_in; (void)out_size; (void)ws_size;
    const float* x_in   = (const float*)d_in[0];
    const float* qkv_w  = (const float*)d_in[1];
    const float* qkv_b  = (const float*)d_in[2];
    const float* proj_w = (const float*)d_in[3];
    const float* proj_b = (const float*)d_in[4];
    const float* btab   = (const float*)d_in[5];
    const float* n1g    = (const float*)d_in[6];
    const float* n1b    = (const float*)d_in[7];
    const float* n2g    = (const float*)d_in[8];
    const float* n2b    = (const float*)d_in[9];
    const float* w1     = (const float*)d_in[10];
    const float* b1     = (const float*)d_in[11];
    const float* w2     = (const float*)d_in[12];
    const float* b2     = (const float*)d_in[13];
    const int*   pidx   = (const int*)d_in[14];
    const float* amask  = (const float*)d_in[15];

    float* x     = (float*)d_out;              // residual stream
    float* stats = (float*)d_ws;               // NTOK*2 floats
    float* region = stats + (size_t)NTOK * 2;  // 14,155,776 floats (56.6 MB)
    float* qkvb  = region;
    float* attnb = region + QKV_CHUNK;
    float* hidb  = region;

    hipMemcpyAsync(x, x_in, (size_t)NTOK * C * sizeof(float),
                   hipMemcpyDeviceToDevice, stream);

    for (int blk = 0; blk < 2; blk++) {
        int roll = blk & 1;
        // ---- attention half ----
        stats_kernel<<<NTOK / 4, 256, 0, stream>>>(x, stats);
        for (int c = 0; c < NCHUNK; c++) {
            int row0 = c * RCHUNK, win0 = c * GWIN;
            gemm_kernel<0><<<dim3(576 / 64, RCHUNK / 64), 256, 0, stream>>>(
                x, qkv_w + (size_t)blk * C * 576, qkv_b + blk * 576, qkvb,
                stats, n1g + blk * C, n1b + blk * C, 576, C, row0, roll);
            attn_kernel<<<dim3(GWIN, NHEADS), 192, 0, stream>>>(
                qkvb, btab + (size_t)blk * NPOS * 64 * 6, pidx, amask,
                attnb, win0, roll);
            gemm_kernel<1><<<dim3(192 / 64, RCHUNK / 64), 256, 0, stream>>>(
                attnb, proj_w + (size_t)blk * C * C, proj_b + blk * C, x,
                nullptr, nullptr, nullptr, 192, C, row0, roll);
        }
        // ---- MLP half ----
        stats_kernel<<<NTOK / 4, 256, 0, stream>>>(x, stats);
        for (int c = 0; c < NCHUNK; c++) {
            int row0 = c * RCHUNK;
            gemm_kernel<2><<<dim3(768 / 64, RCHUNK / 64), 256, 0, stream>>>(
                x, w1 + (size_t)blk * C * 768, b1 + blk * 768, hidb,
                stats, n2g + blk * C, n2b + blk * C, 768, C, row0, 0);
            gemm_kernel<3><<<dim3(192 / 64, RCHUNK / 64), 256, 0, stream>>>(
                hidb, w2 + (size_t)blk * 768 * C, b2 + blk * C, x,
                nullptr, nullptr, nullptr, 192, 768, row0, 0);
        }
    }
}

// Round 3
// 4992.099 us; speedup vs baseline: 1.7721x; 1.7721x over previous
//
#include <hip/hip_runtime.h>
#include <math.h>

#define TZ 8
#define TH 96
#define TW 192
#define C 192
#define NHEADS 6
#define HDIM 32
#define LW 144
#define NWIN 1024
#define NTOK 147456
#define NPOS 3312
#define QSCALE 0.17677669529663687f

#define GWIN 128
#define NCHUNK 8
#define RCHUNK (GWIN * LW)          // 18432 rows per chunk

typedef unsigned short u16;
typedef __attribute__((ext_vector_type(8))) short bf8_t;
typedef __attribute__((ext_vector_type(4))) float f4_t;

__device__ __forceinline__ float bf2f(u16 u) {
    union { unsigned int i; float f; } c; c.i = ((unsigned int)u) << 16; return c.f;
}
__device__ __forceinline__ u16 f2bf(float f) {
    union { float f; unsigned int i; } c; c.f = f;
    unsigned int x = c.i;
    x += 0x7fffu + ((x >> 16) & 1u);   // RNE
    return (u16)(x >> 16);
}

// windowed row -> token (with optional roll). Row r in [0, NTOK).
__device__ __forceinline__ int win_row_to_token(int r, int roll) {
    int wi = r / LW, l = r % LW;
    int nz = wi >> 8, nh = (wi >> 4) & 15, nw = wi & 15;
    int iz = l / 72, rr = l % 72, ih = rr / 12, iw = rr % 12;
    int z = nz * 2 + iz, h = nh * 6 + ih, w = nw * 12 + iw;
    if (roll) {
        z = (z + 1) & 7;
        h += 3; if (h >= TH) h -= TH;
        w += 6; if (w >= TW) w -= TW;
    }
    return (z * TH + h) * TW + w;
}

// ---------------- per-token LN stats ----------------
__global__ __launch_bounds__(256) void stats_kernel(
    const float* __restrict__ x, float* __restrict__ stats)
{
    int wave = threadIdx.x >> 6;
    int lane = threadIdx.x & 63;
    int t = blockIdx.x * 4 + wave;
    const float* xr = x + (size_t)t * C;
    float v0 = xr[lane], v1 = xr[lane + 64], v2 = xr[lane + 128];
    float s = v0 + v1 + v2;
    float sq = v0 * v0 + v1 * v1 + v2 * v2;
    #pragma unroll
    for (int off = 32; off > 0; off >>= 1) {
        s  += __shfl_xor(s, off, 64);
        sq += __shfl_xor(sq, off, 64);
    }
    if (lane == 0) {
        float mean = s * (1.0f / 192.0f);
        float var  = sq * (1.0f / 192.0f) - mean * mean;
        stats[t * 2]     = mean;
        stats[t * 2 + 1] = rsqrtf(var + 1e-5f);
    }
}

// ---------------- bias table materialization: biasf[wt][head][i][j] (bf16) ----------------
__global__ __launch_bounds__(256) void biasmat_kernel(
    const float* __restrict__ btab, const int* __restrict__ pidx,
    u16* __restrict__ biasf)
{
    int wt = blockIdx.x, head = blockIdx.y;
    size_t obase = ((size_t)wt * 6 + head) * (LW * LW);
    for (int idx = threadIdx.x; idx < LW * LW; idx += 256) {
        int p = pidx[idx];
        biasf[obase + idx] = f2bf(btab[((size_t)p * 64 + wt) * 6 + head]);
    }
}

// ---------------- fp32 tiled GEMM, 64x64 tile, 4x4 microtile ----------------
// MODE 0: QKV  : A = LN1(x) window-gathered fp32; OUT bf16 chunk, q-scale
// MODE 1: PROJ : A = attn chunk bf16; epilogue scatter-add x[token] += acc+bias
// MODE 2: MLP1 : A = LN2(x) fp32; OUT bf16 chunk with exact GELU
// MODE 3: MLP2 : A = hidden chunk bf16; epilogue x[row] += acc+bias
template <int MODE>
__global__ __launch_bounds__(256) void gemm_kernel(
    const void* __restrict__ Avoid, const float* __restrict__ Bw,
    const float* __restrict__ bias, void* __restrict__ Cvoid,
    const float* __restrict__ stats, const float* __restrict__ lng,
    const float* __restrict__ lnb, int N, int K, int row0, int roll)
{
    __shared__ float As[16][64];
    __shared__ float Bs[16][64];
    int tid = threadIdx.x;
    int tx = tid & 15, ty = tid >> 4;
    int mb = blockIdx.y * 64, nb = blockIdx.x * 64;
    float acc[4][4] = {};
    int am = tid >> 2, ak = (tid & 3) << 2;
    int bk = tid >> 4, bn = (tid & 15) << 2;

    const float* Af = nullptr;
    const u16* Ab = nullptr;
    float mean = 0.0f, rstd = 0.0f;
    if (MODE == 0 || MODE == 2) {
        int gm = row0 + mb + am;
        int src = (MODE == 0) ? win_row_to_token(gm, roll) : gm;
        Af = (const float*)Avoid + (size_t)src * C;
        mean = stats[src * 2];
        rstd = stats[src * 2 + 1];
    } else {
        Ab = (const u16*)Avoid + (size_t)(mb + am) * K;
    }
    const float* Bptr = Bw + (size_t)bk * N + nb + bn;

    for (int k0 = 0; k0 < K; k0 += 16) {
        float4 av;
        if (MODE == 0 || MODE == 2) {
            av = *(const float4*)(Af + k0 + ak);
            float4 gv = *(const float4*)(lng + k0 + ak);
            float4 bv = *(const float4*)(lnb + k0 + ak);
            av.x = (av.x - mean) * rstd * gv.x + bv.x;
            av.y = (av.y - mean) * rstd * gv.y + bv.y;
            av.z = (av.z - mean) * rstd * gv.z + bv.z;
            av.w = (av.w - mean) * rstd * gv.w + bv.w;
        } else {
            ushort4 u = *(const ushort4*)(Ab + k0 + ak);
            av.x = bf2f(u.x); av.y = bf2f(u.y); av.z = bf2f(u.z); av.w = bf2f(u.w);
        }
        float4 bv4 = *(const float4*)(Bptr + (size_t)k0 * N);
        As[ak + 0][am] = av.x; As[ak + 1][am] = av.y;
        As[ak + 2][am] = av.z; As[ak + 3][am] = av.w;
        *(float4*)&Bs[bk][bn] = bv4;
        __syncthreads();
        #pragma unroll
        for (int kk = 0; kk < 16; kk++) {
            float4 a4 = *(const float4*)&As[kk][ty << 2];
            float4 b4 = *(const float4*)&Bs[kk][tx << 2];
            float a[4] = {a4.x, a4.y, a4.z, a4.w};
            float bb[4] = {b4.x, b4.y, b4.z, b4.w};
            #pragma unroll
            for (int i = 0; i < 4; i++)
                #pragma unroll
                for (int j = 0; j < 4; j++)
                    acc[i][j] += a[i] * bb[j];
        }
        __syncthreads();
    }

    #pragma unroll
    for (int i = 0; i < 4; i++) {
        int m = mb + (ty << 2) + i;
        if (MODE == 1) {
            int t = win_row_to_token(row0 + m, roll);
            float* xrow = (float*)Cvoid + (size_t)t * C;
            #pragma unroll
            for (int j = 0; j < 4; j++) {
                int n = nb + (tx << 2) + j;
                xrow[n] += acc[i][j] + bias[n];
            }
        } else if (MODE == 3) {
            float* xrow = (float*)Cvoid + (size_t)(row0 + m) * C;
            #pragma unroll
            for (int j = 0; j < 4; j++) {
                int n = nb + (tx << 2) + j;
                xrow[n] += acc[i][j] + bias[n];
            }
        } else {
            u16* crow = (u16*)Cvoid + (size_t)m * N;
            int n0 = nb + (tx << 2);
            float vals[4];
            #pragma unroll
            for (int j = 0; j < 4; j++) {
                float v = acc[i][j] + bias[n0 + j];
                if (MODE == 0) {
                    if (n0 + j < 192) v *= QSCALE;
                } else {  // MODE 2: exact GELU
                    v = 0.5f * v * (1.0f + erff(v * 0.70710678118654752f));
                }
                vals[j] = v;
            }
            ushort4 o;
            o.x = f2bf(vals[0]); o.y = f2bf(vals[1]);
            o.z = f2bf(vals[2]); o.w = f2bf(vals[3]);
            *(ushort4*)&crow[n0] = o;
        }
    }
}

// ---------------- MFMA attention: one block (3 waves) per (window, head) ----------------
// Wave w handles i-tiles {3w, 3w+1, 3w+2}. S via mfma 16x16x32 bf16 (K=HDIM=32),
// full-row softmax in registers (no recompute), P->LDS->A-frag, PV with keys
// zero-padded 144->160 (5 mfma per (i-tile, d-tile)).
__global__ __launch_bounds__(192) void attn_kernel(
    const u16* __restrict__ qkvb, const u16* __restrict__ biasf,
    u16* __restrict__ attnb, int win0, int roll)
{
    __shared__ u16 Qs[144 * 40];   // [row][dim], stride 40 (80B, 16B-aligned, <=2-way)
    __shared__ u16 Ks[144 * 40];
    __shared__ u16 Vt[32 * 168];   // [dim][key], keys padded/zeroed 144..159
    __shared__ u16 Ps[3 * 16 * 168]; // per-wave P buffer [16][168]
    __shared__ int region[144];

    int wl = blockIdx.x, head = blockIdx.y;
    int wi = win0 + wl, wt = wi & 63;
    int tid = threadIdx.x;

    const u16* base = qkvb + (size_t)wl * LW * 576;
    for (int idx = tid; idx < 144 * 32; idx += 192) {
        int l = idx >> 5, d = idx & 31;
        const u16* row = base + (size_t)l * 576 + head * 32;
        Qs[l * 40 + d] = row[d];
        Ks[l * 40 + d] = row[192 + d];
        Vt[d * 168 + l] = row[384 + d];
    }
    for (int idx = tid; idx < 32 * 24; idx += 192) {
        int d = idx / 24, c2 = 144 + idx % 24;
        Vt[d * 168 + c2] = 0;
    }
    for (int idx = tid; idx < 48 * 24; idx += 192) {
        int rw = idx / 24, c2 = 144 + idx % 24;
        Ps[rw * 168 + c2] = 0;
    }
    if (tid < 144) {
        int nz = wi >> 8, nh = (wi >> 4) & 15, nw = wi & 15;
        int iz = tid / 72, rr = tid % 72, ih = rr / 12, iw = rr % 12;
        int z = nz * 2 + iz, h = nh * 6 + ih, w = nw * 12 + iw;
        int rz = (z < 6) ? 0 : ((z < 7) ? 1 : 2);
        int rh = (h < 90) ? 0 : ((h < 93) ? 1 : 2);
        int rw2 = (w < 180) ? 0 : ((w < 186) ? 1 : 2);
        region[tid] = rz * 9 + rh * 3 + rw2;
    }
    __syncthreads();

    int wave = tid >> 6, lane = tid & 63;
    int lr = lane & 15, g = lane >> 4;
    u16* Pbuf = &Ps[wave * 16 * 168];

    for (int itl = 0; itl < 3; itl++) {
        int it = wave * 3 + itl;
        bf8_t aQ = *(const bf8_t*)&Qs[(it * 16 + lr) * 40 + g * 8];
        f4_t s[9];
        #pragma unroll
        for (int jt = 0; jt < 9; jt++) {
            bf8_t bK = *(const bf8_t*)&Ks[(jt * 16 + lr) * 40 + g * 8];
            f4_t z4 = {0.f, 0.f, 0.f, 0.f};
            s[jt] = __builtin_amdgcn_mfma_f32_16x16x32_bf16(aQ, bK, z4, 0, 0, 0);
        }
        int rowbase = it * 16 + g * 4;
        const u16* bb = biasf + ((size_t)(wt * 6 + head) * LW + rowbase) * LW + lr;
        int regRow[4], regCol[9];
        if (roll) {
            #pragma unroll
            for (int r = 0; r < 4; r++) regRow[r] = region[rowbase + r];
            #pragma unroll
            for (int jt = 0; jt < 9; jt++) regCol[jt] = region[jt * 16 + lr];
        }
        float m4[4] = {-1e30f, -1e30f, -1e30f, -1e30f};
        #pragma unroll
        for (int jt = 0; jt < 9; jt++)
            #pragma unroll
            for (int r = 0; r < 4; r++) {
                float v = s[jt][r] + bf2f(bb[r * LW + jt * 16]);
                if (roll && (regCol[jt] != regRow[r])) v -= 100.0f;
                s[jt][r] = v;
                m4[r] = fmaxf(m4[r], v);
            }
        #pragma unroll
        for (int off = 1; off < 16; off <<= 1)
            #pragma unroll
            for (int r = 0; r < 4; r++)
                m4[r] = fmaxf(m4[r], __shfl_xor(m4[r], off, 64));
        float l4[4] = {0.f, 0.f, 0.f, 0.f};
        #pragma unroll
        for (int jt = 0; jt < 9; jt++)
            #pragma unroll
            for (int r = 0; r < 4; r++) {
                float p = __expf(s[jt][r] - m4[r]);
                s[jt][r] = p;
                l4[r] += p;
            }
        #pragma unroll
        for (int off = 1; off < 16; off <<= 1)
            #pragma unroll
            for (int r = 0; r < 4; r++)
                l4[r] += __shfl_xor(l4[r], off, 64);
        float inv4[4];
        #pragma unroll
        for (int r = 0; r < 4; r++) inv4[r] = 1.0f / l4[r];

        __syncthreads();   // prior PV reads of Pbuf done before overwrite
        #pragma unroll
        for (int jt = 0; jt < 9; jt++)
            #pragma unroll
            for (int r = 0; r < 4; r++)
                Pbuf[(g * 4 + r) * 168 + jt * 16 + lr] = f2bf(s[jt][r] * inv4[r]);
        __syncthreads();   // P visible before A-frag reads

        #pragma unroll
        for (int dt = 0; dt < 2; dt++) {
            f4_t acc = {0.f, 0.f, 0.f, 0.f};
            #pragma unroll
            for (int kt = 0; kt < 5; kt++) {
                bf8_t aP = *(const bf8_t*)&Pbuf[lr * 168 + kt * 32 + g * 8];
                bf8_t bV = *(const bf8_t*)&Vt[(dt * 16 + lr) * 168 + kt * 32 + g * 8];
                acc = __builtin_amdgcn_mfma_f32_16x16x32_bf16(aP, bV, acc, 0, 0, 0);
            }
            #pragma unroll
            for (int r = 0; r < 4; r++)
                attnb[(size_t)(wl * LW + rowbase + r) * 192 + head * 32 + dt * 16 + lr]
                    = f2bf(acc[r]);
        }
    }
}

extern "C" void kernel_launch(void* const* d_in, const int* in_sizes, int n_in,
                              void* d_out, int out_size, void* d_ws, size_t ws_size,
                              hipStream_t stream)
{
    (void)in_sizes; (void)n_in; (void)out_size; (void)ws_size;
    const float* x_in   = (const float*)d_in[0];
    const float* qkv_w  = (const float*)d_in[1];
    const float* qkv_b  = (const float*)d_in[2];
    const float* proj_w = (const float*)d_in[3];
    const float* proj_b = (const float*)d_in[4];
    const float* btab   = (const float*)d_in[5];
    const float* n1g    = (const float*)d_in[6];
    const float* n1b    = (const float*)d_in[7];
    const float* n2g    = (const float*)d_in[8];
    const float* n2b    = (const float*)d_in[9];
    const float* w1     = (const float*)d_in[10];
    const float* b1     = (const float*)d_in[11];
    const float* w2     = (const float*)d_in[12];
    const float* b2     = (const float*)d_in[13];
    const int*   pidx   = (const int*)d_in[14];

    float* x     = (float*)d_out;
    float* stats = (float*)d_ws;                          // NTOK*2 fp32 (1.18 MB)
    u16* biasf   = (u16*)(stats + (size_t)NTOK * 2);      // 64*6*144*144 bf16 (15.9 MB)
    u16* qkvb    = biasf + (size_t)64 * 6 * LW * LW;      // RCHUNK*576 bf16 (21.2 MB)
    u16* attnb   = qkvb + (size_t)RCHUNK * 576;           // RCHUNK*192 bf16 (7.1 MB)
    u16* hidb    = qkvb;                                  // RCHUNK*768 bf16 (28.3 MB, overlaps)

    hipMemcpyAsync(x, x_in, (size_t)NTOK * C * sizeof(float),
                   hipMemcpyDeviceToDevice, stream);

    for (int blk = 0; blk < 2; blk++) {
        int roll = blk & 1;
        biasmat_kernel<<<dim3(64, 6), 256, 0, stream>>>(
            btab + (size_t)blk * NPOS * 64 * 6, pidx, biasf);
        // ---- attention half ----
        stats_kernel<<<NTOK / 4, 256, 0, stream>>>(x, stats);
        for (int c = 0; c < NCHUNK; c++) {
            int row0 = c * RCHUNK, win0 = c * GWIN;
            gemm_kernel<0><<<dim3(9, RCHUNK / 64), 256, 0, stream>>>(
                x, qkv_w + (size_t)blk * C * 576, qkv_b + blk * 576, qkvb,
                stats, n1g + blk * C, n1b + blk * C, 576, C, row0, roll);
            attn_kernel<<<dim3(GWIN, NHEADS), 192, 0, stream>>>(
                qkvb, biasf, attnb, win0, roll);
            gemm_kernel<1><<<dim3(3, RCHUNK / 64), 256, 0, stream>>>(
                attnb, proj_w + (size_t)blk * C * C, proj_b + blk * C, x,
                nullptr, nullptr, nullptr, 192, C, row0, roll);
        }
        // ---- MLP half ----
        stats_kernel<<<NTOK / 4, 256, 0, stream>>>(x, stats);
        for (int c = 0; c < NCHUNK; c++) {
            int row0 = c * RCHUNK;
            gemm_kernel<2><<<dim3(12, RCHUNK / 64), 256, 0, stream>>>(
                x, w1 + (size_t)blk * C * 768, b1 + blk * 768, hidb,
                stats, n2g + blk * C, n2b + blk * C, 768, C, row0, 0);
            gemm_kernel<3><<<dim3(3, RCHUNK / 64), 256, 0, stream>>>(
                hidb, w2 + (size_t)blk * 768 * C, b2 + blk * C, x,
                nullptr, nullptr, nullptr, 192, 768, row0, 0);
        }
    }
}

// Round 4
// 1883.418 us; speedup vs baseline: 4.6971x; 2.6506x over previous
//
#include <hip/hip_runtime.h>
#include <math.h>

#define TZ 8
#define TH 96
#define TW 192
#define C 192
#define NHEADS 6
#define HDIM 32
#define LW 144
#define NWIN 1024
#define NTOK 147456
#define NPOS 3312
#define QSCALE 0.17677669529663687f

#define GWIN 128
#define NCHUNK 8
#define RCHUNK (GWIN * LW)          // 18432 rows per chunk

typedef unsigned short u16;
typedef __attribute__((ext_vector_type(8))) short bf8_t;
typedef __attribute__((ext_vector_type(4))) float f4_t;

__device__ __forceinline__ float bf2f(u16 u) {
    union { unsigned int i; float f; } c; c.i = ((unsigned int)u) << 16; return c.f;
}
__device__ __forceinline__ u16 f2bf(float f) {
    union { float f; unsigned int i; } c; c.f = f;
    unsigned int x = c.i;
    x += 0x7fffu + ((x >> 16) & 1u);   // RNE
    return (u16)(x >> 16);
}

// windowed row -> token (with optional roll). Row r in [0, NTOK).
__device__ __forceinline__ int win_row_to_token(int r, int roll) {
    int wi = r / LW, l = r % LW;
    int nz = wi >> 8, nh = (wi >> 4) & 15, nw = wi & 15;
    int iz = l / 72, rr = l % 72, ih = rr / 12, iw = rr % 12;
    int z = nz * 2 + iz, h = nh * 6 + ih, w = nw * 12 + iw;
    if (roll) {
        z = (z + 1) & 7;
        h += 3; if (h >= TH) h -= TH;
        w += 6; if (w >= TW) w -= TW;
    }
    return (z * TH + h) * TW + w;
}

// ---------------- fused LN (+gather/roll) -> bf16 chunk, one wave per row ----------------
__global__ __launch_bounds__(256) void ln_kernel(
    const float* __restrict__ x, const float* __restrict__ g,
    const float* __restrict__ b, u16* __restrict__ xnc,
    int row0, int windowed, int roll)
{
    int wave = threadIdx.x >> 6;
    int lane = threadIdx.x & 63;
    int dl = blockIdx.x * 4 + wave;          // chunk-local row
    int d = row0 + dl;
    int src = windowed ? win_row_to_token(d, roll) : d;
    const float* xr = x + (size_t)src * C;
    float v0 = xr[lane], v1 = xr[lane + 64], v2 = xr[lane + 128];
    float s = v0 + v1 + v2;
    float sq = v0 * v0 + v1 * v1 + v2 * v2;
    #pragma unroll
    for (int off = 32; off > 0; off >>= 1) {
        s  += __shfl_xor(s, off, 64);
        sq += __shfl_xor(sq, off, 64);
    }
    float mean = s * (1.0f / 192.0f);
    float var  = sq * (1.0f / 192.0f) - mean * mean;
    float rstd = rsqrtf(var + 1e-5f);
    u16* orow = xnc + (size_t)dl * C;
    orow[lane]       = f2bf((v0 - mean) * rstd * g[lane]       + b[lane]);
    orow[lane + 64]  = f2bf((v1 - mean) * rstd * g[lane + 64]  + b[lane + 64]);
    orow[lane + 128] = f2bf((v2 - mean) * rstd * g[lane + 128] + b[lane + 128]);
}

// ---------------- weight transpose + bf16 convert: WT[n][k] = W[k][n] ----------------
__global__ __launch_bounds__(256) void tconv_kernel(
    const float* __restrict__ W, u16* __restrict__ WT, int K, int N)
{
    int idx = blockIdx.x * 256 + threadIdx.x;
    if (idx >= N * K) return;
    int n = idx / K, k = idx % K;
    WT[idx] = f2bf(W[(size_t)k * N + n]);
}

// ---------------- bias table materialization: biasf[wt][head][i][j] (bf16) ----------------
__global__ __launch_bounds__(256) void biasmat_kernel(
    const float* __restrict__ btab, const int* __restrict__ pidx,
    u16* __restrict__ biasf)
{
    int wt = blockIdx.x, head = blockIdx.y;
    size_t obase = ((size_t)wt * 6 + head) * (LW * LW);
    for (int idx = threadIdx.x; idx < LW * LW; idx += 256) {
        int p = pidx[idx];
        biasf[obase + idx] = f2bf(btab[((size_t)p * 64 + wt) * 6 + head]);
    }
}

// ---------------- bf16 MFMA GEMM: tile 128x64, BK=64, 4 waves (2x2) ----------------
// A: [Mchunk][K] bf16 contiguous.  BT: [N][K] bf16.  C epilogue by MODE:
// MODE 0: QKV  -> qkvb bf16, (acc+bias)*QSCALE for cols<192
// MODE 1: PROJ -> x[token] += acc+bias (window-reverse + un-roll scatter)
// MODE 2: MLP1 -> hidb bf16, exact GELU
// MODE 3: MLP2 -> x[row] += acc+bias
template <int MODE>
__global__ __launch_bounds__(256) void mm_kernel(
    const u16* __restrict__ A, const u16* __restrict__ BT,
    const float* __restrict__ bias, void* __restrict__ Cvoid,
    int N, int K, int row0, int roll)
{
    __shared__ alignas(16) u16 As[128 * 72];   // [m][k], stride 72 (144B)
    __shared__ alignas(16) u16 Bs[64 * 72];    // [n][k], stride 72
    int tid = threadIdx.x;
    int mb = blockIdx.y * 128, nb = blockIdx.x * 64;
    int wave = tid >> 6, lane = tid & 63;
    int mh = wave >> 1, nh = wave & 1;         // wave tile 64(M) x 32(N)
    int lr = lane & 15, g = lane >> 4;

    f4_t acc[4][2];
    #pragma unroll
    for (int mi = 0; mi < 4; mi++)
        #pragma unroll
        for (int ni = 0; ni < 2; ni++)
            acc[mi][ni] = (f4_t){0.f, 0.f, 0.f, 0.f};

    for (int k0 = 0; k0 < K; k0 += 64) {
        // stage A: 128 rows x 64 k = 1024 x 8-u16 chunks
        #pragma unroll
        for (int it = 0; it < 4; it++) {
            int idx = it * 256 + tid;
            int r = idx >> 3, kc = idx & 7;
            *(bf8_t*)&As[r * 72 + kc * 8] =
                *(const bf8_t*)&A[(size_t)(mb + r) * K + k0 + kc * 8];
        }
        // stage B: 64 rows x 64 k = 512 chunks
        #pragma unroll
        for (int it = 0; it < 2; it++) {
            int idx = it * 256 + tid;
            int r = idx >> 3, kc = idx & 7;
            *(bf8_t*)&Bs[r * 72 + kc * 8] =
                *(const bf8_t*)&BT[(size_t)(nb + r) * K + k0 + kc * 8];
        }
        __syncthreads();
        #pragma unroll
        for (int ks = 0; ks < 2; ks++) {
            bf8_t bfr[2];
            #pragma unroll
            for (int ni = 0; ni < 2; ni++)
                bfr[ni] = *(const bf8_t*)&Bs[(nh * 32 + ni * 16 + lr) * 72 + ks * 32 + g * 8];
            #pragma unroll
            for (int mi = 0; mi < 4; mi++) {
                bf8_t afr = *(const bf8_t*)&As[(mh * 64 + mi * 16 + lr) * 72 + ks * 32 + g * 8];
                #pragma unroll
                for (int ni = 0; ni < 2; ni++)
                    acc[mi][ni] = __builtin_amdgcn_mfma_f32_16x16x32_bf16(
                        afr, bfr[ni], acc[mi][ni], 0, 0, 0);
            }
        }
        __syncthreads();
    }

    // epilogue. C layout: col = lane&15, row = (lane>>4)*4 + reg
    #pragma unroll
    for (int mi = 0; mi < 4; mi++) {
        int rbase = mb + mh * 64 + mi * 16 + g * 4;   // chunk-local
        int tok[4];
        if (MODE == 1) {
            #pragma unroll
            for (int r = 0; r < 4; r++)
                tok[r] = win_row_to_token(row0 + rbase + r, roll);
        }
        #pragma unroll
        for (int ni = 0; ni < 2; ni++) {
            int col = nb + nh * 32 + ni * 16 + lr;
            float bb = bias[col];
            #pragma unroll
            for (int r = 0; r < 4; r++) {
                float v = acc[mi][ni][r] + bb;
                if (MODE == 0) {
                    if (col < 192) v *= QSCALE;
                    ((u16*)Cvoid)[(size_t)(rbase + r) * 576 + col] = f2bf(v);
                } else if (MODE == 1) {
                    ((float*)Cvoid)[(size_t)tok[r] * C + col] += v;
                } else if (MODE == 2) {
                    v = 0.5f * v * (1.0f + erff(v * 0.70710678118654752f));
                    ((u16*)Cvoid)[(size_t)(rbase + r) * 768 + col] = f2bf(v);
                } else {
                    ((float*)Cvoid)[(size_t)(row0 + rbase + r) * C + col] += v;
                }
            }
        }
    }
}

// ---------------- MFMA attention (unchanged from round 3) ----------------
__global__ __launch_bounds__(192) void attn_kernel(
    const u16* __restrict__ qkvb, const u16* __restrict__ biasf,
    u16* __restrict__ attnb, int win0, int roll)
{
    __shared__ alignas(16) u16 Qs[144 * 40];
    __shared__ alignas(16) u16 Ks[144 * 40];
    __shared__ alignas(16) u16 Vt[32 * 168];
    __shared__ alignas(16) u16 Ps[3 * 16 * 168];
    __shared__ int region[144];

    int wl = blockIdx.x, head = blockIdx.y;
    int wi = win0 + wl, wt = wi & 63;
    int tid = threadIdx.x;

    const u16* base = qkvb + (size_t)wl * LW * 576;
    for (int idx = tid; idx < 144 * 32; idx += 192) {
        int l = idx >> 5, d = idx & 31;
        const u16* row = base + (size_t)l * 576 + head * 32;
        Qs[l * 40 + d] = row[d];
        Ks[l * 40 + d] = row[192 + d];
        Vt[d * 168 + l] = row[384 + d];
    }
    for (int idx = tid; idx < 32 * 24; idx += 192) {
        int d = idx / 24, c2 = 144 + idx % 24;
        Vt[d * 168 + c2] = 0;
    }
    for (int idx = tid; idx < 48 * 24; idx += 192) {
        int rw = idx / 24, c2 = 144 + idx % 24;
        Ps[rw * 168 + c2] = 0;
    }
    if (tid < 144) {
        int nz = wi >> 8, nh = (wi >> 4) & 15, nw = wi & 15;
        int iz = tid / 72, rr = tid % 72, ih = rr / 12, iw = rr % 12;
        int z = nz * 2 + iz, h = nh * 6 + ih, w = nw * 12 + iw;
        int rz = (z < 6) ? 0 : ((z < 7) ? 1 : 2);
        int rh = (h < 90) ? 0 : ((h < 93) ? 1 : 2);
        int rw2 = (w < 180) ? 0 : ((w < 186) ? 1 : 2);
        region[tid] = rz * 9 + rh * 3 + rw2;
    }
    __syncthreads();

    int wave = tid >> 6, lane = tid & 63;
    int lr = lane & 15, g = lane >> 4;
    u16* Pbuf = &Ps[wave * 16 * 168];

    for (int itl = 0; itl < 3; itl++) {
        int it = wave * 3 + itl;
        bf8_t aQ = *(const bf8_t*)&Qs[(it * 16 + lr) * 40 + g * 8];
        f4_t s[9];
        #pragma unroll
        for (int jt = 0; jt < 9; jt++) {
            bf8_t bK = *(const bf8_t*)&Ks[(jt * 16 + lr) * 40 + g * 8];
            f4_t z4 = {0.f, 0.f, 0.f, 0.f};
            s[jt] = __builtin_amdgcn_mfma_f32_16x16x32_bf16(aQ, bK, z4, 0, 0, 0);
        }
        int rowbase = it * 16 + g * 4;
        const u16* bb = biasf + ((size_t)(wt * 6 + head) * LW + rowbase) * LW + lr;
        int regRow[4], regCol[9];
        if (roll) {
            #pragma unroll
            for (int r = 0; r < 4; r++) regRow[r] = region[rowbase + r];
            #pragma unroll
            for (int jt = 0; jt < 9; jt++) regCol[jt] = region[jt * 16 + lr];
        }
        float m4[4] = {-1e30f, -1e30f, -1e30f, -1e30f};
        #pragma unroll
        for (int jt = 0; jt < 9; jt++)
            #pragma unroll
            for (int r = 0; r < 4; r++) {
                float v = s[jt][r] + bf2f(bb[r * LW + jt * 16]);
                if (roll && (regCol[jt] != regRow[r])) v -= 100.0f;
                s[jt][r] = v;
                m4[r] = fmaxf(m4[r], v);
            }
        #pragma unroll
        for (int off = 1; off < 16; off <<= 1)
            #pragma unroll
            for (int r = 0; r < 4; r++)
                m4[r] = fmaxf(m4[r], __shfl_xor(m4[r], off, 64));
        float l4[4] = {0.f, 0.f, 0.f, 0.f};
        #pragma unroll
        for (int jt = 0; jt < 9; jt++)
            #pragma unroll
            for (int r = 0; r < 4; r++) {
                float p = __expf(s[jt][r] - m4[r]);
                s[jt][r] = p;
                l4[r] += p;
            }
        #pragma unroll
        for (int off = 1; off < 16; off <<= 1)
            #pragma unroll
            for (int r = 0; r < 4; r++)
                l4[r] += __shfl_xor(l4[r], off, 64);
        float inv4[4];
        #pragma unroll
        for (int r = 0; r < 4; r++) inv4[r] = 1.0f / l4[r];

        __syncthreads();
        #pragma unroll
        for (int jt = 0; jt < 9; jt++)
            #pragma unroll
            for (int r = 0; r < 4; r++)
                Pbuf[(g * 4 + r) * 168 + jt * 16 + lr] = f2bf(s[jt][r] * inv4[r]);
        __syncthreads();

        #pragma unroll
        for (int dt = 0; dt < 2; dt++) {
            f4_t acc = {0.f, 0.f, 0.f, 0.f};
            #pragma unroll
            for (int kt = 0; kt < 5; kt++) {
                bf8_t aP = *(const bf8_t*)&Pbuf[lr * 168 + kt * 32 + g * 8];
                bf8_t bV = *(const bf8_t*)&Vt[(dt * 16 + lr) * 168 + kt * 32 + g * 8];
                acc = __builtin_amdgcn_mfma_f32_16x16x32_bf16(aP, bV, acc, 0, 0, 0);
            }
            #pragma unroll
            for (int r = 0; r < 4; r++)
                attnb[(size_t)(wl * LW + rowbase + r) * 192 + head * 32 + dt * 16 + lr]
                    = f2bf(acc[r]);
        }
    }
}

extern "C" void kernel_launch(void* const* d_in, const int* in_sizes, int n_in,
                              void* d_out, int out_size, void* d_ws, size_t ws_size,
                              hipStream_t stream)
{
    (void)in_sizes; (void)n_in; (void)out_size; (void)ws_size;
    const float* x_in   = (const float*)d_in[0];
    const float* qkv_w  = (const float*)d_in[1];
    const float* qkv_b  = (const float*)d_in[2];
    const float* proj_w = (const float*)d_in[3];
    const float* proj_b = (const float*)d_in[4];
    const float* btab   = (const float*)d_in[5];
    const float* n1g    = (const float*)d_in[6];
    const float* n1b    = (const float*)d_in[7];
    const float* n2g    = (const float*)d_in[8];
    const float* n2b    = (const float*)d_in[9];
    const float* w1     = (const float*)d_in[10];
    const float* b1     = (const float*)d_in[11];
    const float* w2     = (const float*)d_in[12];
    const float* b2     = (const float*)d_in[13];
    const int*   pidx   = (const int*)d_in[14];

    float* x   = (float*)d_out;
    u16* biasf = (u16*)d_ws;                             // 7,962,624 u16 (15.9 MB)
    u16* wT    = biasf + (size_t)64 * 6 * LW * LW;       //   884,736 u16 ( 1.8 MB)
    u16* xnc   = wT + 884736;                            // 3,538,944 u16 ( 7.1 MB)
    u16* qkvb  = xnc + (size_t)RCHUNK * C;               // 10,616,832 u16 (21.2 MB)
    u16* attnb = qkvb + (size_t)RCHUNK * 576;            // 3,538,944 u16 ( 7.1 MB)
    u16* hidb  = qkvb;                                   // RCHUNK*768 (overlaps exactly)

    // per-block transposed-weight offsets (u16)
    const size_t WBLK = 442368;   // 576*192 + 192*192 + 768*192 + 192*768
    const size_t OQKV = 0, OPROJ = 110592, OW1 = 147456, OW2 = 294912;

    hipMemcpyAsync(x, x_in, (size_t)NTOK * C * sizeof(float),
                   hipMemcpyDeviceToDevice, stream);

    // one-time weight transpose/convert (both blocks)
    for (int blk = 0; blk < 2; blk++) {
        u16* wb = wT + blk * WBLK;
        tconv_kernel<<<(576 * 192 + 255) / 256, 256, 0, stream>>>(
            qkv_w + (size_t)blk * C * 576, wb + OQKV, C, 576);
        tconv_kernel<<<(192 * 192 + 255) / 256, 256, 0, stream>>>(
            proj_w + (size_t)blk * C * C, wb + OPROJ, C, 192);
        tconv_kernel<<<(768 * 192 + 255) / 256, 256, 0, stream>>>(
            w1 + (size_t)blk * C * 768, wb + OW1, C, 768);
        tconv_kernel<<<(192 * 768 + 255) / 256, 256, 0, stream>>>(
            w2 + (size_t)blk * 768 * C, wb + OW2, 768, 192);
    }

    for (int blk = 0; blk < 2; blk++) {
        int roll = blk & 1;
        u16* wb = wT + blk * WBLK;
        biasmat_kernel<<<dim3(64, 6), 256, 0, stream>>>(
            btab + (size_t)blk * NPOS * 64 * 6, pidx, biasf);
        // ---- attention half ----
        for (int c = 0; c < NCHUNK; c++) {
            int row0 = c * RCHUNK, win0 = c * GWIN;
            ln_kernel<<<RCHUNK / 4, 256, 0, stream>>>(
                x, n1g + blk * C, n1b + blk * C, xnc, row0, 1, roll);
            mm_kernel<0><<<dim3(9, RCHUNK / 128), 256, 0, stream>>>(
                xnc, wb + OQKV, qkv_b + blk * 576, qkvb, 576, C, row0, roll);
            attn_kernel<<<dim3(GWIN, NHEADS), 192, 0, stream>>>(
                qkvb, biasf, attnb, win0, roll);
            mm_kernel<1><<<dim3(3, RCHUNK / 128), 256, 0, stream>>>(
                attnb, wb + OPROJ, proj_b + blk * C, x, 192, C, row0, roll);
        }
        // ---- MLP half ----
        for (int c = 0; c < NCHUNK; c++) {
            int row0 = c * RCHUNK;
            ln_kernel<<<RCHUNK / 4, 256, 0, stream>>>(
                x, n2g + blk * C, n2b + blk * C, xnc, row0, 0, 0);
            mm_kernel<2><<<dim3(12, RCHUNK / 128), 256, 0, stream>>>(
                xnc, wb + OW1, b1 + blk * 768, hidb, 768, C, row0, 0);
            mm_kernel<3><<<dim3(3, RCHUNK / 128), 256, 0, stream>>>(
                hidb, wb + OW2, b2 + blk * C, x, 192, 768, row0, 0);
        }
    }
}